// Round 4
// baseline (1644.686 us; speedup 1.0000x reference)
//
#include <hip/hip_runtime.h>

typedef unsigned short u16;
typedef short bf16x8 __attribute__((ext_vector_type(8)));
typedef float f32x4 __attribute__((ext_vector_type(4)));
typedef u16 u16x4 __attribute__((ext_vector_type(4)));

#define SCALE_Q 0.044194173824159216f   // 1/sqrt(512)

// barrier WITHOUT vmcnt drain: global prefetch loads stay in flight.
// lgkmcnt(0) drains LDS ops for cross-wave visibility; "memory" clobber
// stops compiler reordering of memory ops across it.
#define BAR() asm volatile("s_waitcnt lgkmcnt(0)\n\ts_barrier" ::: "memory")

__device__ __forceinline__ u16 f2b(float f){   // fp32 -> bf16 RNE
  unsigned u = __float_as_uint(f);
  u += 0x7fffu + ((u >> 16) & 1u);
  return (u16)(u >> 16);
}

__device__ __forceinline__ void gload16(const void* g, void* l){
  __builtin_amdgcn_global_load_lds(
      (const __attribute__((address_space(1))) void*)g,
      (__attribute__((address_space(3))) void*)l, 16, 0, 0);
}

__device__ __forceinline__ float qsum16(float v){
  v += __shfl_xor(v, 1); v += __shfl_xor(v, 2);
  v += __shfl_xor(v, 4); v += __shfl_xor(v, 8);
  return v;
}

// ---------------- GroupNorm stats: one block per (b, group) ----------------
__global__ __launch_bounds__(256) void gn_stats(const float* __restrict__ x,
                                                float* __restrict__ stats){
  int bg = blockIdx.x;
  const float4* p4 = (const float4*)(x + (size_t)bg * 65536);
  float s = 0.f, ss = 0.f;
  for (int i = threadIdx.x; i < 16384; i += 256){
    float4 v = p4[i];
    s  += v.x + v.y + v.z + v.w;
    ss += v.x*v.x + v.y*v.y + v.z*v.z + v.w*v.w;
  }
  for (int off = 32; off; off >>= 1){
    s  += __shfl_down(s, off);
    ss += __shfl_down(ss, off);
  }
  __shared__ float as_[4], bs_[4];
  int wid = threadIdx.x >> 6, lid = threadIdx.x & 63;
  if (lid == 0){ as_[wid] = s; bs_[wid] = ss; }
  __syncthreads();
  if (threadIdx.x == 0){
    float S = as_[0]+as_[1]+as_[2]+as_[3], SS = bs_[0]+bs_[1]+bs_[2]+bs_[3];
    float mean = S * (1.f/65536.f);
    float var  = SS * (1.f/65536.f) - mean*mean;
    stats[2*bg]   = mean;
    stats[2*bg+1] = rsqrtf(var + 1e-6f);
  }
}

// ------- normalize + affine + transpose [b,c,N] -> t[b,N,c] (bf16) ---------
__global__ __launch_bounds__(256) void gn_apply_T(const float* __restrict__ x,
                                                  const float* __restrict__ stats,
                                                  const float* __restrict__ gamma,
                                                  const float* __restrict__ beta,
                                                  u16* __restrict__ t){
  __shared__ float tile[32][33];
  int nb = blockIdx.x, cb = blockIdx.y, b = blockIdx.z;
  int tx = threadIdx.x & 31, ty = threadIdx.x >> 5;
  int n0 = nb * 32, c0 = cb * 32;
  #pragma unroll
  for (int i = 0; i < 4; i++){
    int ch = c0 + ty + i*8;
    float mean = stats[2*((b<<5) + (ch>>4))];
    float rstd = stats[2*((b<<5) + (ch>>4)) + 1];
    float v = x[(((size_t)b*512 + ch) << 12) + n0 + tx];
    tile[ty + i*8][tx] = (v - mean) * rstd * gamma[ch] + beta[ch];
  }
  __syncthreads();
  #pragma unroll
  for (int i = 0; i < 4; i++){
    int n = n0 + ty + i*8;
    int ch = c0 + tx;
    t[((size_t)((b<<12) + n))*512 + ch] = f2b(tile[tx][ty + i*8]);
  }
}

// ---------------- fp32 -> bf16 weight conversion (4 matrices) --------------
__global__ __launch_bounds__(256) void w2bf(const float* __restrict__ a,
                                            const float* __restrict__ b,
                                            const float* __restrict__ c,
                                            const float* __restrict__ d,
                                            u16* __restrict__ o){
  int idx = blockIdx.x * 256 + threadIdx.x;
  int which = idx >> 16;
  const float4* src = (const float4*)(which == 0 ? a : which == 1 ? b : which == 2 ? c : d);
  float4 v = src[idx & 65535];
  u16x4 pk;
  pk.x = f2b(v.x); pk.y = f2b(v.y); pk.z = f2b(v.z); pk.w = f2b(v.w);
  *(u16x4*)(o + (size_t)idx*4) = pk;
}

// ------------- fused QKV gemm: grid (128, 12); y>>2 selects matrix ---------
// mat 0 -> Q [b,tok,c]*SCALE_Q
// mat 1 -> K tiled [b][tile128][ks16][kr32][ch32]   (attn-ready)
// mat 2 -> V tiled [b][tile128][c512][kv32]         (attn-ready)
__global__ __launch_bounds__(256, 2) void qkv_gemm(const u16* __restrict__ A,
                                                   const u16* __restrict__ Wcat,
                                                   const float* __restrict__ qbias,
                                                   const float* __restrict__ kbias,
                                                   const float* __restrict__ vbias,
                                                   u16* __restrict__ qo,
                                                   u16* __restrict__ ko,
                                                   u16* __restrict__ vo){
  __shared__ __align__(16) u16 As[128*32];
  __shared__ __align__(16) u16 Bs[128*32];
  const int t = threadIdx.x;
  const int w = t >> 6, ln = t & 63;
  const int wr = w >> 1, wc = w & 1;
  const int q4 = ln >> 4, l15 = ln & 15;
  const int y = blockIdx.y;
  const int mat = y >> 2, yb = y & 3;
  const u16* Ab = A    + (size_t)blockIdx.x * 128 * 512;
  const u16* Bb = Wcat + (size_t)y * 128 * 512;
  f32x4 acc[4][4];
  #pragma unroll
  for (int i = 0; i < 4; i++)
    #pragma unroll
    for (int j = 0; j < 4; j++){
      acc[i][j][0]=0.f; acc[i][j][1]=0.f; acc[i][j][2]=0.f; acc[i][j][3]=0.f;
    }
  for (int kt = 0; kt < 16; ++kt){
    #pragma unroll
    for (int i = 0; i < 2; i++){
      int idx = i*256 + t;
      gload16(Ab + (size_t)(idx>>2)*512 + kt*32 + (idx&3)*8, As + (size_t)idx*8);
      gload16(Bb + (size_t)(idx>>2)*512 + kt*32 + (idx&3)*8, Bs + (size_t)idx*8);
    }
    __syncthreads();
    bf16x8 af[4], bf[4];
    #pragma unroll
    for (int mt = 0; mt < 4; mt++)
      af[mt] = *(const bf16x8*)(As + (wr*64 + mt*16 + l15)*32 + q4*8);
    #pragma unroll
    for (int nt = 0; nt < 4; nt++)
      bf[nt] = *(const bf16x8*)(Bs + (wc*64 + nt*16 + l15)*32 + q4*8);
    #pragma unroll
    for (int mt = 0; mt < 4; mt++)
      #pragma unroll
      for (int nt = 0; nt < 4; nt++)
        acc[mt][nt] = __builtin_amdgcn_mfma_f32_16x16x32_bf16(af[mt], bf[nt], acc[mt][nt], 0, 0, 0);
    __syncthreads();
  }
  const int row0 = blockIdx.x*128 + wr*64;
  const int col0 = yb*128 + wc*64;
  if (mat == 0){
    #pragma unroll
    for (int nt = 0; nt < 4; nt++){
      int n = col0 + nt*16 + l15;
      float bv = qbias[n];
      #pragma unroll
      for (int mt = 0; mt < 4; mt++){
        int m0 = row0 + mt*16 + q4*4;
        #pragma unroll
        for (int r = 0; r < 4; r++)
          qo[(size_t)(m0 + r)*512 + n] = f2b((acc[mt][nt][r] + bv) * SCALE_Q);
      }
    }
  } else if (mat == 1){
    #pragma unroll
    for (int nt = 0; nt < 4; nt++){
      int n = col0 + nt*16 + l15;
      float bv = kbias[n];
      #pragma unroll
      for (int mt = 0; mt < 4; mt++){
        int m0 = row0 + mt*16 + q4*4;
        #pragma unroll
        for (int r = 0; r < 4; r++){
          int m = m0 + r;
          int bb = m >> 12, tok = m & 4095;
          size_t addr = ((((size_t)bb*128 + (tok>>5))*16 + (n>>5))*32 + (tok&31))*32 + (n&31);
          ko[addr] = f2b(acc[mt][nt][r] + bv);
        }
      }
    }
  } else {
    #pragma unroll
    for (int nt = 0; nt < 4; nt++){
      int n = col0 + nt*16 + l15;
      float bv = vbias[n];
      #pragma unroll
      for (int mt = 0; mt < 4; mt++){
        int m0 = row0 + mt*16 + q4*4;
        int bb = m0 >> 12, tok = m0 & 4095;
        u16x4 pk;
        pk.x = f2b(acc[mt][nt][0] + bv);
        pk.y = f2b(acc[mt][nt][1] + bv);
        pk.z = f2b(acc[mt][nt][2] + bv);
        pk.w = f2b(acc[mt][nt][3] + bv);
        size_t base = (((size_t)bb*128 + (tok>>5))*512 + n)*32 + (tok&31);
        *(u16x4*)(vo + base) = pk;
      }
    }
  }
}

// ----------- out-proj gemm + bias + residual + transpose (fp32 out) --------
__global__ __launch_bounds__(256, 2) void out_gemm(const u16* __restrict__ A,
                                                   const u16* __restrict__ Bw,
                                                   const float* __restrict__ bias,
                                                   float* __restrict__ out,
                                                   const float* __restrict__ resid){
  __shared__ __align__(16) u16 As[128*32];
  __shared__ __align__(16) u16 Bs[128*32];
  const int t = threadIdx.x;
  const int w = t >> 6, ln = t & 63;
  const int wr = w >> 1, wc = w & 1;
  const int q4 = ln >> 4, l15 = ln & 15;
  const u16* Ab = A  + (size_t)blockIdx.x * 128 * 512;
  const u16* Bb = Bw + (size_t)blockIdx.y * 128 * 512;
  f32x4 acc[4][4];
  #pragma unroll
  for (int i = 0; i < 4; i++)
    #pragma unroll
    for (int j = 0; j < 4; j++){
      acc[i][j][0]=0.f; acc[i][j][1]=0.f; acc[i][j][2]=0.f; acc[i][j][3]=0.f;
    }
  for (int kt = 0; kt < 16; ++kt){
    #pragma unroll
    for (int i = 0; i < 2; i++){
      int idx = i*256 + t;
      gload16(Ab + (size_t)(idx>>2)*512 + kt*32 + (idx&3)*8, As + (size_t)idx*8);
      gload16(Bb + (size_t)(idx>>2)*512 + kt*32 + (idx&3)*8, Bs + (size_t)idx*8);
    }
    __syncthreads();
    bf16x8 af[4], bf[4];
    #pragma unroll
    for (int mt = 0; mt < 4; mt++)
      af[mt] = *(const bf16x8*)(As + (wr*64 + mt*16 + l15)*32 + q4*8);
    #pragma unroll
    for (int nt = 0; nt < 4; nt++)
      bf[nt] = *(const bf16x8*)(Bs + (wc*64 + nt*16 + l15)*32 + q4*8);
    #pragma unroll
    for (int mt = 0; mt < 4; mt++)
      #pragma unroll
      for (int nt = 0; nt < 4; nt++)
        acc[mt][nt] = __builtin_amdgcn_mfma_f32_16x16x32_bf16(af[mt], bf[nt], acc[mt][nt], 0, 0, 0);
    __syncthreads();
  }
  const int row0 = blockIdx.x*128 + wr*64;
  const int col0 = blockIdx.y*128 + wc*64;
  #pragma unroll
  for (int nt = 0; nt < 4; nt++){
    int n = col0 + nt*16 + l15;
    float bv = bias[n];
    #pragma unroll
    for (int mt = 0; mt < 4; mt++){
      int m0 = row0 + mt*16 + q4*4;
      int bb = m0 >> 12, tok = m0 & 4095;
      size_t base = (((size_t)(bb*512 + n)) << 12) + tok;
      float4 xr = *(const float4*)(resid + base);
      float4 ov;
      ov.x = acc[mt][nt][0] + bv + xr.x;
      ov.y = acc[mt][nt][1] + bv + xr.y;
      ov.z = acc[mt][nt][2] + bv + xr.z;
      ov.w = acc[mt][nt][3] + bv + xr.w;
      *(float4*)(out + base) = ov;
    }
  }
}

// ---------------------------- flash attention ------------------------------
// q [b,tok,512] (pre-scaled); kt tiled [b][128][ks16][kr32][ch32];
// vt tiled [b][128][c512][kv32]; out O bf16 [b,tok,512].
// BM=32, BN=32, 256 threads (4 waves), 2 blocks/CU.
// Max-free softmax (scores |s|<~2, exp safe in fp32): per-lane partial l,
// single cross-lane reduce in epilogue. K/V staged via VGPR prefetch +
// ds_write with XOR-swizzled chunks (all LDS accesses <=2-way); barriers
// drain lgkm only, so the j+2 global prefetch stays in flight across them.
__global__ __launch_bounds__(256, 2) void attn_fwd(const u16* __restrict__ q,
                                                   const u16* __restrict__ kt,
                                                   const u16* __restrict__ vt,
                                                   u16* __restrict__ outO){
  __shared__ __align__(16) u16 Kt[16*32*32];   // [ks][kr32][ch32] swizzled 32KB
  __shared__ __align__(16) u16 Vt[512*32];     // [c][kv32] swizzled        32KB
  __shared__ __align__(16) u16 Pb[32*40];      // [qrow][40]               2.5KB
  __shared__ __align__(16) float lL[64];       // [ch][row32]

  const int t = threadIdx.x, w = t >> 6, ln = t & 63;
  const int q4 = ln >> 4, l15 = ln & 15;
  const int rt = w >> 1, chh = w & 1;          // S role: row-tile, col-half
  const int b = blockIdx.y, q0 = blockIdx.x * 32;
  const float4* K4 = (const float4*)(kt + ((size_t)b << 21)); // 128 tiles x 2048 chunks
  const float4* V4 = (const float4*)(vt + ((size_t)b << 21));

  // per-thread staging indices
  const int ksb  = t >> 7;                     // 0/1: ks = 2*i + ksb
  const int krw  = (16*w + (ln >> 2)) & 31;    // K row this thread writes
  const int hk   = ln & 3;
  const int kelem = krw*32 + ((hk ^ ((krw >> 1) & 3)) << 3);
  const int cv0  = 128*w + (ln >> 2);          // V channel base (own PV strip)
  const int vswz = ((hk ^ ((ln >> 3) & 3)) << 3);

  // Q fragments: rows q0 + rt*16 + l15, all 512 ch (64 VGPR)
  bf16x8 qf[16];
  {
    const u16* qr = q + ((size_t)b << 21) + (size_t)(q0 + rt*16 + l15) * 512;
    #pragma unroll
    for (int ks = 0; ks < 16; ks++) qf[ks] = *(const bf16x8*)(qr + ks*32 + q4*8);
  }
  f32x4 oacc[2][8];
  #pragma unroll
  for (int i = 0; i < 2; i++)
    #pragma unroll
    for (int j = 0; j < 8; j++){
      oacc[i][j][0]=0.f; oacc[i][j][1]=0.f; oacc[i][j][2]=0.f; oacc[i][j][3]=0.f;
    }
  f32x4 lrow; lrow[0]=0.f; lrow[1]=0.f; lrow[2]=0.f; lrow[3]=0.f;

  float4 vpk[8], vpv[8];
  // prologue: tile 0 -> LDS; tile 1 -> regs
  #pragma unroll
  for (int i = 0; i < 8; i++) vpk[i] = K4[i*256 + t];
  #pragma unroll
  for (int i = 0; i < 8; i++) vpv[i] = V4[512*w + 64*i + ln];
  #pragma unroll
  for (int i = 0; i < 8; i++) *(float4*)&Kt[(ksb + 2*i)*1024 + kelem] = vpk[i];
  #pragma unroll
  for (int i = 0; i < 8; i++) *(float4*)&Vt[(cv0 + 16*i)*32 + vswz] = vpv[i];
  #pragma unroll
  for (int i = 0; i < 8; i++) vpk[i] = K4[2048 + i*256 + t];
  #pragma unroll
  for (int i = 0; i < 8; i++) vpv[i] = V4[2048 + 512*w + 64*i + ln];
  BAR();

  #pragma unroll 1
  for (int j = 0; j < 128; ++j){
    // ---- S = Q K^T : wave (rt,chh): rows rt*16, cols chh*16 ----
    f32x4 s; s[0]=0.f; s[1]=0.f; s[2]=0.f; s[3]=0.f;
    const int krow = chh*16 + l15;
    const int kchunk = ((q4 ^ ((l15 >> 1) & 3)) << 3);
    #pragma unroll
    for (int ks = 0; ks < 16; ks++){
      bf16x8 kf = *(const bf16x8*)&Kt[ks*1024 + krow*32 + kchunk];
      s = __builtin_amdgcn_mfma_f32_16x16x32_bf16(qf[ks], kf, s, 0, 0, 0);
    }
    // ---- max-free softmax: e = exp(s), per-lane partial l ----
    #pragma unroll
    for (int r = 0; r < 4; r++){
      float e = __expf(s[r]);
      lrow[r] += e;
      Pb[(rt*16 + q4*4 + r)*40 + chh*16 + l15] = f2b(e);
    }
    BAR();                                   // B1: Pb visible, Kt reads done
    // ---- write K tile j+1, issue K loads j+2 (stay in flight) ----
    #pragma unroll
    for (int i = 0; i < 8; i++) *(float4*)&Kt[(ksb + 2*i)*1024 + kelem] = vpk[i];
    {
      const size_t tb = (size_t)((j + 2) & 127) * 2048;
      #pragma unroll
      for (int i = 0; i < 8; i++) vpk[i] = K4[tb + i*256 + t];
    }
    // ---- PV: O += P V, wave owns cols [128w, 128w+128) ----
    {
      bf16x8 pf0 = *(const bf16x8*)&Pb[l15*40 + q4*8];
      bf16x8 pf1 = *(const bf16x8*)&Pb[(16 + l15)*40 + q4*8];
      #pragma unroll
      for (int ct = 0; ct < 8; ct++){
        const int c = 128*w + ct*16 + l15;
        bf16x8 vf = *(const bf16x8*)&Vt[c*32 + ((q4 ^ ((l15 >> 1) & 3)) << 3)];
        oacc[0][ct] = __builtin_amdgcn_mfma_f32_16x16x32_bf16(pf0, vf, oacc[0][ct], 0, 0, 0);
        oacc[1][ct] = __builtin_amdgcn_mfma_f32_16x16x32_bf16(pf1, vf, oacc[1][ct], 0, 0, 0);
      }
    }
    // ---- write V tile j+1 (own strip, own reads done), issue V loads j+2 ----
    #pragma unroll
    for (int i = 0; i < 8; i++) *(float4*)&Vt[(cv0 + 16*i)*32 + vswz] = vpv[i];
    {
      const size_t tb = (size_t)((j + 2) & 127) * 2048;
      #pragma unroll
      for (int i = 0; i < 8; i++) vpv[i] = V4[tb + 512*w + 64*i + ln];
    }
    BAR();                                   // B2: Kt(j+1) visible to all
  }

  // ---- epilogue: reduce l, divide, store ----
  {
    f32x4 ls;
    #pragma unroll
    for (int r = 0; r < 4; r++) ls[r] = qsum16(lrow[r]);
    if (l15 == 0) *(f32x4*)&lL[chh*32 + rt*16 + q4*4] = ls;
  }
  __syncthreads();
  #pragma unroll
  for (int rr = 0; rr < 2; rr++){
    #pragma unroll
    for (int r = 0; r < 4; r++){
      int row = rr*16 + q4*4 + r;
      float inv = 1.f / (lL[row] + lL[32 + row]);
      u16* op = outO + ((size_t)b << 21) + (size_t)(q0 + row)*512 + 128*w + l15;
      #pragma unroll
      for (int ct = 0; ct < 8; ct++)
        op[ct*16] = f2b(oacc[rr][ct][r] * inv);
    }
  }
}

extern "C" void kernel_launch(void* const* d_in, const int* in_sizes, int n_in,
                              void* d_out, int out_size, void* d_ws, size_t ws_size,
                              hipStream_t stream){
  const float* x     = (const float*)d_in[0];
  const float* gamma = (const float*)d_in[1];
  const float* beta  = (const float*)d_in[2];
  const float* wq_w  = (const float*)d_in[3];
  const float* wq_b  = (const float*)d_in[4];
  const float* wk_w  = (const float*)d_in[5];
  const float* wk_b  = (const float*)d_in[6];
  const float* wv_w  = (const float*)d_in[7];
  const float* wv_b  = (const float*)d_in[8];
  const float* out_w = (const float*)d_in[9];
  const float* out_b = (const float*)d_in[10];

  char* ws = (char*)d_ws;
  float* stats = (float*)ws;                                   // 1 KB
  u16* tbuf = (u16*)(ws + 4096);                               // 16 MB (t, then O)
  size_t off = 4096 + (size_t)16*1024*1024;
  u16* Wcat = (u16*)(ws + off); off += (size_t)4*512*512*2;    // 2 MB
  u16* qb   = (u16*)(ws + off); off += (size_t)16*1024*1024;
  u16* ktb  = (u16*)(ws + off); off += (size_t)16*1024*1024;   // K tiled
  u16* vtb  = (u16*)(ws + off); off += (size_t)16*1024*1024;   // V tiled

  gn_stats<<<128, 256, 0, stream>>>(x, stats);
  gn_apply_T<<<dim3(128, 16, 4), 256, 0, stream>>>(x, stats, gamma, beta, tbuf);
  w2bf<<<1024, 256, 0, stream>>>(wq_w, wk_w, wv_w, out_w, Wcat);
  u16* Wo = Wcat + 3*512*512;
  qkv_gemm<<<dim3(128, 12), 256, 0, stream>>>(tbuf, Wcat, wq_b, wk_b, wv_b,
                                              qb, ktb, vtb);
  attn_fwd<<<dim3(128, 4), 256, 0, stream>>>(qb, ktb, vtb, tbuf);
  out_gemm<<<dim3(128, 4), 256, 0, stream>>>(tbuf, Wo, out_b, (float*)d_out, x);
}

// Round 5
// 407.474 us; speedup vs baseline: 4.0363x; 4.0363x over previous
//
#include <hip/hip_runtime.h>

typedef unsigned short u16;
typedef short bf16x8 __attribute__((ext_vector_type(8)));
typedef float f32x4 __attribute__((ext_vector_type(4)));
typedef u16 u16x4 __attribute__((ext_vector_type(4)));

#define SCALE_Q 0.044194173824159216f   // 1/sqrt(512)

// barrier WITHOUT vmcnt drain (lgkm only): in-flight global/DMA ops survive.
#define BAR() asm volatile("s_waitcnt lgkmcnt(0)\n\ts_barrier" ::: "memory")

__device__ __forceinline__ u16 f2b(float f){   // fp32 -> bf16 RNE
  unsigned u = __float_as_uint(f);
  u += 0x7fffu + ((u >> 16) & 1u);
  return (u16)(u >> 16);
}

__device__ __forceinline__ void gload16(const void* g, void* l){
  __builtin_amdgcn_global_load_lds(
      (const __attribute__((address_space(1))) void*)g,
      (__attribute__((address_space(3))) void*)l, 16, 0, 0);
}

__device__ __forceinline__ float qsum16(float v){
  v += __shfl_xor(v, 1); v += __shfl_xor(v, 2);
  v += __shfl_xor(v, 4); v += __shfl_xor(v, 8);
  return v;
}

// ---------------- GroupNorm stats: one block per (b, group) ----------------
__global__ __launch_bounds__(256) void gn_stats(const float* __restrict__ x,
                                                float* __restrict__ stats){
  int bg = blockIdx.x;
  const float4* p4 = (const float4*)(x + (size_t)bg * 65536);
  float s = 0.f, ss = 0.f;
  for (int i = threadIdx.x; i < 16384; i += 256){
    float4 v = p4[i];
    s  += v.x + v.y + v.z + v.w;
    ss += v.x*v.x + v.y*v.y + v.z*v.z + v.w*v.w;
  }
  for (int off = 32; off; off >>= 1){
    s  += __shfl_down(s, off);
    ss += __shfl_down(ss, off);
  }
  __shared__ float as_[4], bs_[4];
  int wid = threadIdx.x >> 6, lid = threadIdx.x & 63;
  if (lid == 0){ as_[wid] = s; bs_[wid] = ss; }
  __syncthreads();
  if (threadIdx.x == 0){
    float S = as_[0]+as_[1]+as_[2]+as_[3], SS = bs_[0]+bs_[1]+bs_[2]+bs_[3];
    float mean = S * (1.f/65536.f);
    float var  = SS * (1.f/65536.f) - mean*mean;
    stats[2*bg]   = mean;
    stats[2*bg+1] = rsqrtf(var + 1e-6f);
  }
}

// ------- normalize + affine + transpose [b,c,N] -> t[b,N,c] (bf16) ---------
__global__ __launch_bounds__(256) void gn_apply_T(const float* __restrict__ x,
                                                  const float* __restrict__ stats,
                                                  const float* __restrict__ gamma,
                                                  const float* __restrict__ beta,
                                                  u16* __restrict__ t){
  __shared__ float tile[32][33];
  int nb = blockIdx.x, cb = blockIdx.y, b = blockIdx.z;
  int tx = threadIdx.x & 31, ty = threadIdx.x >> 5;
  int n0 = nb * 32, c0 = cb * 32;
  #pragma unroll
  for (int i = 0; i < 4; i++){
    int ch = c0 + ty + i*8;
    float mean = stats[2*((b<<5) + (ch>>4))];
    float rstd = stats[2*((b<<5) + (ch>>4)) + 1];
    float v = x[(((size_t)b*512 + ch) << 12) + n0 + tx];
    tile[ty + i*8][tx] = (v - mean) * rstd * gamma[ch] + beta[ch];
  }
  __syncthreads();
  #pragma unroll
  for (int i = 0; i < 4; i++){
    int n = n0 + ty + i*8;
    int ch = c0 + tx;
    t[((size_t)((b<<12) + n))*512 + ch] = f2b(tile[tx][ty + i*8]);
  }
}

// ---------------- fp32 -> bf16 weight conversion (4 matrices) --------------
__global__ __launch_bounds__(256) void w2bf(const float* __restrict__ a,
                                            const float* __restrict__ b,
                                            const float* __restrict__ c,
                                            const float* __restrict__ d,
                                            u16* __restrict__ o){
  int idx = blockIdx.x * 256 + threadIdx.x;
  int which = idx >> 16;
  const float4* src = (const float4*)(which == 0 ? a : which == 1 ? b : which == 2 ? c : d);
  float4 v = src[idx & 65535];
  u16x4 pk;
  pk.x = f2b(v.x); pk.y = f2b(v.y); pk.z = f2b(v.z); pk.w = f2b(v.w);
  *(u16x4*)(o + (size_t)idx*4) = pk;
}

// ------------- fused QKV gemm: grid (128, 12); y>>2 selects matrix ---------
// mat 0 -> Q [b,tok,c]*SCALE_Q
// mat 1 -> K tiled [b][tile128][ks16][kr32][ch32]   (attn-ready)
// mat 2 -> V tiled [b][tile128][c512][kv32]         (attn-ready)
__global__ __launch_bounds__(256, 2) void qkv_gemm(const u16* __restrict__ A,
                                                   const u16* __restrict__ Wcat,
                                                   const float* __restrict__ qbias,
                                                   const float* __restrict__ kbias,
                                                   const float* __restrict__ vbias,
                                                   u16* __restrict__ qo,
                                                   u16* __restrict__ ko,
                                                   u16* __restrict__ vo){
  __shared__ __align__(16) u16 As[128*32];
  __shared__ __align__(16) u16 Bs[128*32];
  const int t = threadIdx.x;
  const int w = t >> 6, ln = t & 63;
  const int wr = w >> 1, wc = w & 1;
  const int q4 = ln >> 4, l15 = ln & 15;
  const int y = blockIdx.y;
  const int mat = y >> 2, yb = y & 3;
  const u16* Ab = A    + (size_t)blockIdx.x * 128 * 512;
  const u16* Bb = Wcat + (size_t)y * 128 * 512;
  f32x4 acc[4][4];
  #pragma unroll
  for (int i = 0; i < 4; i++)
    #pragma unroll
    for (int j = 0; j < 4; j++){
      acc[i][j][0]=0.f; acc[i][j][1]=0.f; acc[i][j][2]=0.f; acc[i][j][3]=0.f;
    }
  for (int kt = 0; kt < 16; ++kt){
    #pragma unroll
    for (int i = 0; i < 2; i++){
      int idx = i*256 + t;
      gload16(Ab + (size_t)(idx>>2)*512 + kt*32 + (idx&3)*8, As + (size_t)idx*8);
      gload16(Bb + (size_t)(idx>>2)*512 + kt*32 + (idx&3)*8, Bs + (size_t)idx*8);
    }
    __syncthreads();
    bf16x8 af[4], bf[4];
    #pragma unroll
    for (int mt = 0; mt < 4; mt++)
      af[mt] = *(const bf16x8*)(As + (wr*64 + mt*16 + l15)*32 + q4*8);
    #pragma unroll
    for (int nt = 0; nt < 4; nt++)
      bf[nt] = *(const bf16x8*)(Bs + (wc*64 + nt*16 + l15)*32 + q4*8);
    #pragma unroll
    for (int mt = 0; mt < 4; mt++)
      #pragma unroll
      for (int nt = 0; nt < 4; nt++)
        acc[mt][nt] = __builtin_amdgcn_mfma_f32_16x16x32_bf16(af[mt], bf[nt], acc[mt][nt], 0, 0, 0);
    __syncthreads();
  }
  const int row0 = blockIdx.x*128 + wr*64;
  const int col0 = yb*128 + wc*64;
  if (mat == 0){
    #pragma unroll
    for (int nt = 0; nt < 4; nt++){
      int n = col0 + nt*16 + l15;
      float bv = qbias[n];
      #pragma unroll
      for (int mt = 0; mt < 4; mt++){
        int m0 = row0 + mt*16 + q4*4;
        #pragma unroll
        for (int r = 0; r < 4; r++)
          qo[(size_t)(m0 + r)*512 + n] = f2b((acc[mt][nt][r] + bv) * SCALE_Q);
      }
    }
  } else if (mat == 1){
    #pragma unroll
    for (int nt = 0; nt < 4; nt++){
      int n = col0 + nt*16 + l15;
      float bv = kbias[n];
      #pragma unroll
      for (int mt = 0; mt < 4; mt++){
        int m0 = row0 + mt*16 + q4*4;
        #pragma unroll
        for (int r = 0; r < 4; r++){
          int m = m0 + r;
          int bb = m >> 12, tok = m & 4095;
          size_t addr = ((((size_t)bb*128 + (tok>>5))*16 + (n>>5))*32 + (tok&31))*32 + (n&31);
          ko[addr] = f2b(acc[mt][nt][r] + bv);
        }
      }
    }
  } else {
    #pragma unroll
    for (int nt = 0; nt < 4; nt++){
      int n = col0 + nt*16 + l15;
      float bv = vbias[n];
      #pragma unroll
      for (int mt = 0; mt < 4; mt++){
        int m0 = row0 + mt*16 + q4*4;
        int bb = m0 >> 12, tok = m0 & 4095;
        u16x4 pk;
        pk.x = f2b(acc[mt][nt][0] + bv);
        pk.y = f2b(acc[mt][nt][1] + bv);
        pk.z = f2b(acc[mt][nt][2] + bv);
        pk.w = f2b(acc[mt][nt][3] + bv);
        size_t base = (((size_t)bb*128 + (tok>>5))*512 + n)*32 + (tok&31);
        *(u16x4*)(vo + base) = pk;
      }
    }
  }
}

// ----------- out-proj gemm + bias + residual + transpose (fp32 out) --------
__global__ __launch_bounds__(256, 2) void out_gemm(const u16* __restrict__ A,
                                                   const u16* __restrict__ Bw,
                                                   const float* __restrict__ bias,
                                                   float* __restrict__ out,
                                                   const float* __restrict__ resid){
  __shared__ __align__(16) u16 As[128*32];
  __shared__ __align__(16) u16 Bs[128*32];
  const int t = threadIdx.x;
  const int w = t >> 6, ln = t & 63;
  const int wr = w >> 1, wc = w & 1;
  const int q4 = ln >> 4, l15 = ln & 15;
  const u16* Ab = A  + (size_t)blockIdx.x * 128 * 512;
  const u16* Bb = Bw + (size_t)blockIdx.y * 128 * 512;
  f32x4 acc[4][4];
  #pragma unroll
  for (int i = 0; i < 4; i++)
    #pragma unroll
    for (int j = 0; j < 4; j++){
      acc[i][j][0]=0.f; acc[i][j][1]=0.f; acc[i][j][2]=0.f; acc[i][j][3]=0.f;
    }
  for (int kt = 0; kt < 16; ++kt){
    #pragma unroll
    for (int i = 0; i < 2; i++){
      int idx = i*256 + t;
      gload16(Ab + (size_t)(idx>>2)*512 + kt*32 + (idx&3)*8, As + (size_t)idx*8);
      gload16(Bb + (size_t)(idx>>2)*512 + kt*32 + (idx&3)*8, Bs + (size_t)idx*8);
    }
    __syncthreads();
    bf16x8 af[4], bf[4];
    #pragma unroll
    for (int mt = 0; mt < 4; mt++)
      af[mt] = *(const bf16x8*)(As + (wr*64 + mt*16 + l15)*32 + q4*8);
    #pragma unroll
    for (int nt = 0; nt < 4; nt++)
      bf[nt] = *(const bf16x8*)(Bs + (wc*64 + nt*16 + l15)*32 + q4*8);
    #pragma unroll
    for (int mt = 0; mt < 4; mt++)
      #pragma unroll
      for (int nt = 0; nt < 4; nt++)
        acc[mt][nt] = __builtin_amdgcn_mfma_f32_16x16x32_bf16(af[mt], bf[nt], acc[mt][nt], 0, 0, 0);
    __syncthreads();
  }
  const int row0 = blockIdx.x*128 + wr*64;
  const int col0 = blockIdx.y*128 + wc*64;
  #pragma unroll
  for (int nt = 0; nt < 4; nt++){
    int n = col0 + nt*16 + l15;
    float bv = bias[n];
    #pragma unroll
    for (int mt = 0; mt < 4; mt++){
      int m0 = row0 + mt*16 + q4*4;
      int bb = m0 >> 12, tok = m0 & 4095;
      size_t base = (((size_t)(bb*512 + n)) << 12) + tok;
      float4 xr = *(const float4*)(resid + base);
      float4 ov;
      ov.x = acc[mt][nt][0] + bv + xr.x;
      ov.y = acc[mt][nt][1] + bv + xr.y;
      ov.z = acc[mt][nt][2] + bv + xr.z;
      ov.w = acc[mt][nt][3] + bv + xr.w;
      *(float4*)(out + base) = ov;
    }
  }
}

// ---------------------------- flash attention ------------------------------
// q [b,tok,512] (pre-scaled); kt tiled [b][128][ks16][kr32][ch32];
// vt tiled [b][128][c512][kv32]; out O bf16 [b,tok,512].
// BM=32, BN=32, 256 threads (4 waves), 2 blocks/CU.
// K: double-buffered LDS via global_load_lds (zero VGPR cost; DMA issued at
//   iter top -> one full iteration of latency cover before the end-barrier's
//   vmcnt(0) drain).  V: fragments read DIRECTLY from L2 (coalesced 1KB/wave,
//   32 transient VGPRs, latency covered by softmax + 2-block TLP).
// Max-free softmax (R4-validated): exp only, per-lane partial l, single
//   reduce in epilogue. Mid-iter barrier is lgkm-only.
__global__ __launch_bounds__(256, 2) void attn_fwd(const u16* __restrict__ q,
                                                   const u16* __restrict__ kt,
                                                   const u16* __restrict__ vt,
                                                   u16* __restrict__ outO){
  __shared__ __align__(16) u16 Kb[2][16384];   // 2 x 32KB, [ks16][kr32][ch32]
  __shared__ __align__(16) u16 Pb[32*40];      // [qrow32][40]  2.5KB
  __shared__ __align__(16) float lL[64];       // [chh][row32]

  const int t = threadIdx.x, w = t >> 6, ln = t & 63;
  const int q4 = ln >> 4, l15 = ln & 15;
  const int rt = w >> 1, chh = w & 1;          // S role: row-tile, col-half
  const int b = blockIdx.y, q0 = blockIdx.x * 32;
  const u16* kbase = kt + ((size_t)b << 21);
  const u16* vbase = vt + ((size_t)b << 21);

  // Q fragments: rows q0 + rt*16 + l15, all 512 ch (64 VGPR)
  bf16x8 qf[16];
  {
    const u16* qr = q + ((size_t)b << 21) + (size_t)(q0 + rt*16 + l15) * 512;
    #pragma unroll
    for (int ks = 0; ks < 16; ks++) qf[ks] = *(const bf16x8*)(qr + ks*32 + q4*8);
  }
  f32x4 oacc[2][8];
  #pragma unroll
  for (int i = 0; i < 2; i++)
    #pragma unroll
    for (int j = 0; j < 8; j++){
      oacc[i][j][0]=0.f; oacc[i][j][1]=0.f; oacc[i][j][2]=0.f; oacc[i][j][3]=0.f;
    }
  f32x4 lrow; lrow[0]=0.f; lrow[1]=0.f; lrow[2]=0.f; lrow[3]=0.f;

  // prologue: DMA K tile 0 into Kb[0]
  #pragma unroll
  for (int i = 0; i < 8; i++){
    int ci = i*256 + t;
    gload16(kbase + (size_t)ci*8, &Kb[0][ci*8]);
  }
  __syncthreads();

  #pragma unroll 1
  for (int j = 0; j < 128; ++j){
    // 1. issue DMA for K tile j+1 (other buffer; overlaps whole iteration)
    {
      const u16* kn = kbase + (size_t)((j + 1) & 127) * 16384;
      u16* kd = Kb[(j + 1) & 1];
      #pragma unroll
      for (int i = 0; i < 8; i++){
        int ci = i*256 + t;
        gload16(kn + (size_t)ci*8, kd + ci*8);
      }
    }
    // 2. S = Q K^T : wave (rt,chh): rows rt*16..+16, kv-cols chh*16..+16
    const u16* Kp = Kb[j & 1];
    f32x4 s; s[0]=0.f; s[1]=0.f; s[2]=0.f; s[3]=0.f;
    {
      const int krow = chh*16 + l15;
      #pragma unroll
      for (int ks = 0; ks < 16; ks++){
        bf16x8 kf = *(const bf16x8*)(Kp + ks*1024 + krow*32 + q4*8);
        s = __builtin_amdgcn_mfma_f32_16x16x32_bf16(qf[ks], kf, s, 0, 0, 0);
      }
    }
    // 3. V fragment loads straight from L2 (tile j); consumed in PV
    bf16x8 vf[8];
    {
      const u16* vtile = vbase + (size_t)j * 16384;
      #pragma unroll
      for (int ct = 0; ct < 8; ct++)
        vf[ct] = *(const bf16x8*)(vtile + (128*w + ct*16 + l15)*32 + q4*8);
    }
    // 4. max-free softmax: e = exp(s), per-lane partial l, P -> LDS
    #pragma unroll
    for (int r = 0; r < 4; r++){
      float e = __expf(s[r]);
      lrow[r] += e;
      Pb[(rt*16 + q4*4 + r)*40 + chh*16 + l15] = f2b(e);
    }
    BAR();                                   // P visible; DMA + vf stay in flight
    // 5. PV: O += P V ; wave owns col strip [128w, 128w+128)
    {
      bf16x8 pf0 = *(const bf16x8*)(Pb + l15*40 + q4*8);
      bf16x8 pf1 = *(const bf16x8*)(Pb + (16 + l15)*40 + q4*8);
      #pragma unroll
      for (int ct = 0; ct < 8; ct++){
        oacc[0][ct] = __builtin_amdgcn_mfma_f32_16x16x32_bf16(pf0, vf[ct], oacc[0][ct], 0, 0, 0);
        oacc[1][ct] = __builtin_amdgcn_mfma_f32_16x16x32_bf16(pf1, vf[ct], oacc[1][ct], 0, 0, 0);
      }
    }
    __syncthreads();                         // drains DMA(j+1) (a full iter old)
  }

  // ---- epilogue: reduce l across lanes + the two col-half waves ----
  {
    f32x4 ls;
    #pragma unroll
    for (int r = 0; r < 4; r++) ls[r] = qsum16(lrow[r]);
    if (l15 == 0) *(f32x4*)&lL[chh*32 + rt*16 + q4*4] = ls;
  }
  __syncthreads();
  #pragma unroll
  for (int rr = 0; rr < 2; rr++){
    #pragma unroll
    for (int r = 0; r < 4; r++){
      int row = rr*16 + q4*4 + r;
      float inv = 1.f / (lL[row] + lL[32 + row]);
      u16* op = outO + ((size_t)b << 21) + (size_t)(q0 + row)*512 + 128*w + l15;
      #pragma unroll
      for (int ct = 0; ct < 8; ct++)
        op[ct*16] = f2b(oacc[rr][ct][r] * inv);
    }
  }
}

extern "C" void kernel_launch(void* const* d_in, const int* in_sizes, int n_in,
                              void* d_out, int out_size, void* d_ws, size_t ws_size,
                              hipStream_t stream){
  const float* x     = (const float*)d_in[0];
  const float* gamma = (const float*)d_in[1];
  const float* beta  = (const float*)d_in[2];
  const float* wq_w  = (const float*)d_in[3];
  const float* wq_b  = (const float*)d_in[4];
  const float* wk_w  = (const float*)d_in[5];
  const float* wk_b  = (const float*)d_in[6];
  const float* wv_w  = (const float*)d_in[7];
  const float* wv_b  = (const float*)d_in[8];
  const float* out_w = (const float*)d_in[9];
  const float* out_b = (const float*)d_in[10];

  char* ws = (char*)d_ws;
  float* stats = (float*)ws;                                   // 1 KB
  u16* tbuf = (u16*)(ws + 4096);                               // 16 MB (t, then O)
  size_t off = 4096 + (size_t)16*1024*1024;
  u16* Wcat = (u16*)(ws + off); off += (size_t)4*512*512*2;    // 2 MB
  u16* qb   = (u16*)(ws + off); off += (size_t)16*1024*1024;
  u16* ktb  = (u16*)(ws + off); off += (size_t)16*1024*1024;   // K tiled
  u16* vtb  = (u16*)(ws + off); off += (size_t)16*1024*1024;   // V tiled

  gn_stats<<<128, 256, 0, stream>>>(x, stats);
  gn_apply_T<<<dim3(128, 16, 4), 256, 0, stream>>>(x, stats, gamma, beta, tbuf);
  w2bf<<<1024, 256, 0, stream>>>(wq_w, wk_w, wv_w, out_w, Wcat);
  u16* Wo = Wcat + 3*512*512;
  qkv_gemm<<<dim3(128, 12), 256, 0, stream>>>(tbuf, Wcat, wq_b, wk_b, wv_b,
                                              qb, ktb, vtb);
  attn_fwd<<<dim3(128, 4), 256, 0, stream>>>(qb, ktb, vtb, tbuf);
  out_gemm<<<dim3(128, 4), 256, 0, stream>>>(tbuf, Wo, out_b, (float*)d_out, x);
}

// Round 6
// 364.521 us; speedup vs baseline: 4.5119x; 1.1178x over previous
//
#include <hip/hip_runtime.h>
#include <hip/hip_fp8.h>

typedef unsigned short u16;
typedef unsigned char u8;
typedef short bf16x8 __attribute__((ext_vector_type(8)));
typedef float f32x4 __attribute__((ext_vector_type(4)));
typedef u16 u16x4 __attribute__((ext_vector_type(4)));

#define SCALE_Q 0.044194173824159216f   // 1/sqrt(512)

// barrier WITHOUT vmcnt drain (lgkm only): in-flight global/DMA ops survive.
#define BAR() asm volatile("s_waitcnt lgkmcnt(0)\n\ts_barrier" ::: "memory")

__device__ __forceinline__ u16 f2b(float f){   // fp32 -> bf16 RNE
  unsigned u = __float_as_uint(f);
  u += 0x7fffu + ((u >> 16) & 1u);
  return (u16)(u >> 16);
}

__device__ __forceinline__ u8 f2e4(float f){   // fp32 -> fp8 e4m3 (OCP)
  return __hip_fp8_e4m3(f).__x;
}

__device__ __forceinline__ void gload16(const void* g, void* l){
  __builtin_amdgcn_global_load_lds(
      (const __attribute__((address_space(1))) void*)g,
      (__attribute__((address_space(3))) void*)l, 16, 0, 0);
}

__device__ __forceinline__ float qsum16(float v){
  v += __shfl_xor(v, 1); v += __shfl_xor(v, 2);
  v += __shfl_xor(v, 4); v += __shfl_xor(v, 8);
  return v;
}

// ---------------- GroupNorm stats: one block per (b, group) ----------------
__global__ __launch_bounds__(256) void gn_stats(const float* __restrict__ x,
                                                float* __restrict__ stats){
  int bg = blockIdx.x;
  const float4* p4 = (const float4*)(x + (size_t)bg * 65536);
  float s = 0.f, ss = 0.f;
  for (int i = threadIdx.x; i < 16384; i += 256){
    float4 v = p4[i];
    s  += v.x + v.y + v.z + v.w;
    ss += v.x*v.x + v.y*v.y + v.z*v.z + v.w*v.w;
  }
  for (int off = 32; off; off >>= 1){
    s  += __shfl_down(s, off);
    ss += __shfl_down(ss, off);
  }
  __shared__ float as_[4], bs_[4];
  int wid = threadIdx.x >> 6, lid = threadIdx.x & 63;
  if (lid == 0){ as_[wid] = s; bs_[wid] = ss; }
  __syncthreads();
  if (threadIdx.x == 0){
    float S = as_[0]+as_[1]+as_[2]+as_[3], SS = bs_[0]+bs_[1]+bs_[2]+bs_[3];
    float mean = S * (1.f/65536.f);
    float var  = SS * (1.f/65536.f) - mean*mean;
    stats[2*bg]   = mean;
    stats[2*bg+1] = rsqrtf(var + 1e-6f);
  }
}

// ------- normalize + affine + transpose [b,c,N] -> t[b,N,c] (bf16) ---------
__global__ __launch_bounds__(256) void gn_apply_T(const float* __restrict__ x,
                                                  const float* __restrict__ stats,
                                                  const float* __restrict__ gamma,
                                                  const float* __restrict__ beta,
                                                  u16* __restrict__ t){
  __shared__ float tile[32][33];
  int nb = blockIdx.x, cb = blockIdx.y, b = blockIdx.z;
  int tx = threadIdx.x & 31, ty = threadIdx.x >> 5;
  int n0 = nb * 32, c0 = cb * 32;
  #pragma unroll
  for (int i = 0; i < 4; i++){
    int ch = c0 + ty + i*8;
    float mean = stats[2*((b<<5) + (ch>>4))];
    float rstd = stats[2*((b<<5) + (ch>>4)) + 1];
    float v = x[(((size_t)b*512 + ch) << 12) + n0 + tx];
    tile[ty + i*8][tx] = (v - mean) * rstd * gamma[ch] + beta[ch];
  }
  __syncthreads();
  #pragma unroll
  for (int i = 0; i < 4; i++){
    int n = n0 + ty + i*8;
    int ch = c0 + tx;
    t[((size_t)((b<<12) + n))*512 + ch] = f2b(tile[tx][ty + i*8]);
  }
}

// ---------------- fp32 -> bf16 weight conversion (4 matrices) --------------
__global__ __launch_bounds__(256) void w2bf(const float* __restrict__ a,
                                            const float* __restrict__ b,
                                            const float* __restrict__ c,
                                            const float* __restrict__ d,
                                            u16* __restrict__ o){
  int idx = blockIdx.x * 256 + threadIdx.x;
  int which = idx >> 16;
  const float4* src = (const float4*)(which == 0 ? a : which == 1 ? b : which == 2 ? c : d);
  float4 v = src[idx & 65535];
  u16x4 pk;
  pk.x = f2b(v.x); pk.y = f2b(v.y); pk.z = f2b(v.z); pk.w = f2b(v.w);
  *(u16x4*)(o + (size_t)idx*4) = pk;
}

// ------------- fused QKV gemm: grid (128, 12); y>>2 selects matrix ---------
// mat 0 -> Q fp8 e4m3 [b,tok,c]  (UNscaled; SCALE applied post-MFMA in attn)
// mat 1 -> K fp8 e4m3 tiled [b][tile128][ks16][kr32][ch32] with chunk swizzle
//          chunk' = (ch>>3) ^ ((kr>>2)&3)  -> conflict-free ds_read_b64
// mat 2 -> V bf16 tiled [b][tile128][c512][kv32]
__global__ __launch_bounds__(256, 2) void qkv_gemm(const u16* __restrict__ A,
                                                   const u16* __restrict__ Wcat,
                                                   const float* __restrict__ qbias,
                                                   const float* __restrict__ kbias,
                                                   const float* __restrict__ vbias,
                                                   u8* __restrict__ qo,
                                                   u8* __restrict__ ko,
                                                   u16* __restrict__ vo){
  __shared__ __align__(16) u16 As[128*32];
  __shared__ __align__(16) u16 Bs[128*32];
  const int t = threadIdx.x;
  const int w = t >> 6, ln = t & 63;
  const int wr = w >> 1, wc = w & 1;
  const int q4 = ln >> 4, l15 = ln & 15;
  const int y = blockIdx.y;
  const int mat = y >> 2, yb = y & 3;
  const u16* Ab = A    + (size_t)blockIdx.x * 128 * 512;
  const u16* Bb = Wcat + (size_t)y * 128 * 512;
  f32x4 acc[4][4];
  #pragma unroll
  for (int i = 0; i < 4; i++)
    #pragma unroll
    for (int j = 0; j < 4; j++){
      acc[i][j][0]=0.f; acc[i][j][1]=0.f; acc[i][j][2]=0.f; acc[i][j][3]=0.f;
    }
  for (int kt = 0; kt < 16; ++kt){
    #pragma unroll
    for (int i = 0; i < 2; i++){
      int idx = i*256 + t;
      gload16(Ab + (size_t)(idx>>2)*512 + kt*32 + (idx&3)*8, As + (size_t)idx*8);
      gload16(Bb + (size_t)(idx>>2)*512 + kt*32 + (idx&3)*8, Bs + (size_t)idx*8);
    }
    __syncthreads();
    bf16x8 af[4], bf[4];
    #pragma unroll
    for (int mt = 0; mt < 4; mt++)
      af[mt] = *(const bf16x8*)(As + (wr*64 + mt*16 + l15)*32 + q4*8);
    #pragma unroll
    for (int nt = 0; nt < 4; nt++)
      bf[nt] = *(const bf16x8*)(Bs + (wc*64 + nt*16 + l15)*32 + q4*8);
    #pragma unroll
    for (int mt = 0; mt < 4; mt++)
      #pragma unroll
      for (int nt = 0; nt < 4; nt++)
        acc[mt][nt] = __builtin_amdgcn_mfma_f32_16x16x32_bf16(af[mt], bf[nt], acc[mt][nt], 0, 0, 0);
    __syncthreads();
  }
  const int row0 = blockIdx.x*128 + wr*64;
  const int col0 = yb*128 + wc*64;
  if (mat == 0){
    #pragma unroll
    for (int nt = 0; nt < 4; nt++){
      int n = col0 + nt*16 + l15;
      float bv = qbias[n];
      #pragma unroll
      for (int mt = 0; mt < 4; mt++){
        int m0 = row0 + mt*16 + q4*4;
        #pragma unroll
        for (int r = 0; r < 4; r++)
          qo[(size_t)(m0 + r)*512 + n] = f2e4(acc[mt][nt][r] + bv);
      }
    }
  } else if (mat == 1){
    #pragma unroll
    for (int nt = 0; nt < 4; nt++){
      int n = col0 + nt*16 + l15;
      float bv = kbias[n];
      int ks = n >> 5, ch = n & 31;
      #pragma unroll
      for (int mt = 0; mt < 4; mt++){
        int m0 = row0 + mt*16 + q4*4;
        #pragma unroll
        for (int r = 0; r < 4; r++){
          int m = m0 + r;
          int bb = m >> 12, tok = m & 4095;
          int kr = tok & 31, tile = tok >> 5;
          int chunk = (ch >> 3) ^ ((kr >> 2) & 3);
          size_t addr = ((((size_t)bb*128 + tile) << 14)) + ks*1024 + kr*32 + chunk*8 + (ch & 7);
          ko[addr] = f2e4(acc[mt][nt][r] + bv);
        }
      }
    }
  } else {
    #pragma unroll
    for (int nt = 0; nt < 4; nt++){
      int n = col0 + nt*16 + l15;
      float bv = vbias[n];
      #pragma unroll
      for (int mt = 0; mt < 4; mt++){
        int m0 = row0 + mt*16 + q4*4;
        int bb = m0 >> 12, tok = m0 & 4095;
        u16x4 pk;
        pk.x = f2b(acc[mt][nt][0] + bv);
        pk.y = f2b(acc[mt][nt][1] + bv);
        pk.z = f2b(acc[mt][nt][2] + bv);
        pk.w = f2b(acc[mt][nt][3] + bv);
        size_t base = (((size_t)bb*128 + (tok>>5))*512 + n)*32 + (tok&31);
        *(u16x4*)(vo + base) = pk;
      }
    }
  }
}

// ----------- out-proj gemm + bias + residual + transpose (fp32 out) --------
__global__ __launch_bounds__(256, 2) void out_gemm(const u16* __restrict__ A,
                                                   const u16* __restrict__ Bw,
                                                   const float* __restrict__ bias,
                                                   float* __restrict__ out,
                                                   const float* __restrict__ resid){
  __shared__ __align__(16) u16 As[128*32];
  __shared__ __align__(16) u16 Bs[128*32];
  const int t = threadIdx.x;
  const int w = t >> 6, ln = t & 63;
  const int wr = w >> 1, wc = w & 1;
  const int q4 = ln >> 4, l15 = ln & 15;
  const u16* Ab = A  + (size_t)blockIdx.x * 128 * 512;
  const u16* Bb = Bw + (size_t)blockIdx.y * 128 * 512;
  f32x4 acc[4][4];
  #pragma unroll
  for (int i = 0; i < 4; i++)
    #pragma unroll
    for (int j = 0; j < 4; j++){
      acc[i][j][0]=0.f; acc[i][j][1]=0.f; acc[i][j][2]=0.f; acc[i][j][3]=0.f;
    }
  for (int kt = 0; kt < 16; ++kt){
    #pragma unroll
    for (int i = 0; i < 2; i++){
      int idx = i*256 + t;
      gload16(Ab + (size_t)(idx>>2)*512 + kt*32 + (idx&3)*8, As + (size_t)idx*8);
      gload16(Bb + (size_t)(idx>>2)*512 + kt*32 + (idx&3)*8, Bs + (size_t)idx*8);
    }
    __syncthreads();
    bf16x8 af[4], bf[4];
    #pragma unroll
    for (int mt = 0; mt < 4; mt++)
      af[mt] = *(const bf16x8*)(As + (wr*64 + mt*16 + l15)*32 + q4*8);
    #pragma unroll
    for (int nt = 0; nt < 4; nt++)
      bf[nt] = *(const bf16x8*)(Bs + (wc*64 + nt*16 + l15)*32 + q4*8);
    #pragma unroll
    for (int mt = 0; mt < 4; mt++)
      #pragma unroll
      for (int nt = 0; nt < 4; nt++)
        acc[mt][nt] = __builtin_amdgcn_mfma_f32_16x16x32_bf16(af[mt], bf[nt], acc[mt][nt], 0, 0, 0);
    __syncthreads();
  }
  const int row0 = blockIdx.x*128 + wr*64;
  const int col0 = blockIdx.y*128 + wc*64;
  #pragma unroll
  for (int nt = 0; nt < 4; nt++){
    int n = col0 + nt*16 + l15;
    float bv = bias[n];
    #pragma unroll
    for (int mt = 0; mt < 4; mt++){
      int m0 = row0 + mt*16 + q4*4;
      int bb = m0 >> 12, tok = m0 & 4095;
      size_t base = (((size_t)(bb*512 + n)) << 12) + tok;
      float4 xr = *(const float4*)(resid + base);
      float4 ov;
      ov.x = acc[mt][nt][0] + bv + xr.x;
      ov.y = acc[mt][nt][1] + bv + xr.y;
      ov.z = acc[mt][nt][2] + bv + xr.z;
      ov.w = acc[mt][nt][3] + bv + xr.w;
      *(float4*)(out + base) = ov;
    }
  }
}

// ---------------------------- flash attention ------------------------------
// q fp8 [b,tok,512] (unscaled); kt fp8 tiled+swizzled [b][128][ks16][kr32][32];
// vt bf16 tiled [b][128][c512][kv32]; out O bf16 [b,tok,512].
// BM=32, BN=32, 256 threads (4 waves), 2 blocks/CU.
// S-phase in fp8 MFMA (halves LDS reads + K traffic + qf regs); scale applied
// post-MFMA (keeps fp8 inputs out of the denormal region). K dbuf via
// global_load_lds, swizzled -> conflict-free ds_read_b64. V issued early
// (pre-S) straight from L2. Max-free softmax (R4/R5-validated).
__global__ __launch_bounds__(256, 2) void attn_fwd(const u8* __restrict__ q,
                                                   const u8* __restrict__ kt,
                                                   const u16* __restrict__ vt,
                                                   u16* __restrict__ outO){
  __shared__ __align__(16) u8 Kb[2][16384];    // 2 x 16KB fp8, swizzled
  __shared__ __align__(16) u16 Pb[32*40];      // [qrow32][40] bf16  2.5KB
  __shared__ __align__(16) float lL[64];       // [chh][row32]

  const int t = threadIdx.x, w = t >> 6, ln = t & 63;
  const int q4 = ln >> 4, l15 = ln & 15;
  const int rt = w >> 1, chh = w & 1;          // S role: row-tile, col-half
  const int b = blockIdx.y, q0 = blockIdx.x * 32;
  const u8*  kbase = kt + ((size_t)b << 21);   // 2 MB per batch
  const u16* vbase = vt + ((size_t)b << 21);   // 2M u16 per batch

  // Q fragments fp8: rows q0 + rt*16 + l15, all 512 ch (32 VGPR)
  long qf[16];
  {
    const u8* qr = q + (size_t)((b<<12) + q0 + rt*16 + l15) * 512;
    #pragma unroll
    for (int ks = 0; ks < 16; ks++) qf[ks] = *(const long*)(qr + ks*32 + q4*8);
  }
  f32x4 oacc[2][8];
  #pragma unroll
  for (int i = 0; i < 2; i++)
    #pragma unroll
    for (int j = 0; j < 8; j++){
      oacc[i][j][0]=0.f; oacc[i][j][1]=0.f; oacc[i][j][2]=0.f; oacc[i][j][3]=0.f;
    }
  f32x4 lrow; lrow[0]=0.f; lrow[1]=0.f; lrow[2]=0.f; lrow[3]=0.f;

  // swizzled K read offsets (constant per lane)
  const int krow = chh*16 + l15;
  const int kcho = (q4 ^ ((krow >> 2) & 3)) << 3;

  // prologue: DMA K tile 0 into Kb[0] (1024 x 16B chunks, 4 per thread)
  #pragma unroll
  for (int i = 0; i < 4; i++){
    int ci = i*256 + t;
    gload16(kbase + (size_t)ci*16, &Kb[0][ci*16]);
  }
  __syncthreads();

  #pragma unroll 1
  for (int j = 0; j < 128; ++j){
    // 1. issue DMA for K tile j+1 (other buffer; full-iter latency cover)
    {
      const u8* kn = kbase + ((size_t)((j + 1) & 127) << 14);
      u8* kd = Kb[(j + 1) & 1];
      #pragma unroll
      for (int i = 0; i < 4; i++){
        int ci = i*256 + t;
        gload16(kn + (size_t)ci*16, kd + ci*16);
      }
    }
    // 2. V fragment loads from L2 EARLY (consumed in PV after softmax)
    bf16x8 vf[8];
    {
      const u16* vtile = vbase + ((size_t)j << 14);
      #pragma unroll
      for (int ct = 0; ct < 8; ct++)
        vf[ct] = *(const bf16x8*)(vtile + (128*w + ct*16 + l15)*32 + q4*8);
    }
    // 3. S = Q K^T (fp8): wave (rt,chh): rows rt*16..+16, kv-cols chh*16..+16
    const u8* Kp = Kb[j & 1];
    f32x4 s; s[0]=0.f; s[1]=0.f; s[2]=0.f; s[3]=0.f;
    #pragma unroll
    for (int ks = 0; ks < 16; ks++){
      long kf = *(const long*)(Kp + ks*1024 + krow*32 + kcho);
      s = __builtin_amdgcn_mfma_f32_16x16x32_fp8_fp8(qf[ks], kf, s, 0, 0, 0);
    }
    // 4. max-free softmax with post-MFMA scaling
    #pragma unroll
    for (int r = 0; r < 4; r++){
      float e = __expf(s[r] * SCALE_Q);
      lrow[r] += e;
      Pb[(rt*16 + q4*4 + r)*40 + chh*16 + l15] = f2b(e);
    }
    BAR();                                   // P visible; DMA + vf in flight
    // 5. PV: O += P V ; wave owns col strip [128w, 128w+128)
    {
      bf16x8 pf0 = *(const bf16x8*)(Pb + l15*40 + q4*8);
      bf16x8 pf1 = *(const bf16x8*)(Pb + (16 + l15)*40 + q4*8);
      #pragma unroll
      for (int ct = 0; ct < 8; ct++){
        oacc[0][ct] = __builtin_amdgcn_mfma_f32_16x16x32_bf16(pf0, vf[ct], oacc[0][ct], 0, 0, 0);
        oacc[1][ct] = __builtin_amdgcn_mfma_f32_16x16x32_bf16(pf1, vf[ct], oacc[1][ct], 0, 0, 0);
      }
    }
    __syncthreads();                         // drains DMA(j+1) (a full iter old)
  }

  // ---- epilogue: reduce l across lanes + the two col-half waves ----
  {
    f32x4 ls;
    #pragma unroll
    for (int r = 0; r < 4; r++) ls[r] = qsum16(lrow[r]);
    if (l15 == 0) *(f32x4*)&lL[chh*32 + rt*16 + q4*4] = ls;
  }
  __syncthreads();
  #pragma unroll
  for (int rr = 0; rr < 2; rr++){
    #pragma unroll
    for (int r = 0; r < 4; r++){
      int row = rr*16 + q4*4 + r;
      float inv = 1.f / (lL[row] + lL[32 + row]);
      u16* op = outO + ((size_t)b << 21) + (size_t)(q0 + row)*512 + 128*w + l15;
      #pragma unroll
      for (int ct = 0; ct < 8; ct++)
        op[ct*16] = f2b(oacc[rr][ct][r] * inv);
    }
  }
}

extern "C" void kernel_launch(void* const* d_in, const int* in_sizes, int n_in,
                              void* d_out, int out_size, void* d_ws, size_t ws_size,
                              hipStream_t stream){
  const float* x     = (const float*)d_in[0];
  const float* gamma = (const float*)d_in[1];
  const float* beta  = (const float*)d_in[2];
  const float* wq_w  = (const float*)d_in[3];
  const float* wq_b  = (const float*)d_in[4];
  const float* wk_w  = (const float*)d_in[5];
  const float* wk_b  = (const float*)d_in[6];
  const float* wv_w  = (const float*)d_in[7];
  const float* wv_b  = (const float*)d_in[8];
  const float* out_w = (const float*)d_in[9];
  const float* out_b = (const float*)d_in[10];

  char* ws = (char*)d_ws;
  float* stats = (float*)ws;                                   // 1 KB
  u16* tbuf = (u16*)(ws + 4096);                               // 16 MB (t, then O)
  size_t off = 4096 + (size_t)16*1024*1024;
  u16* Wcat = (u16*)(ws + off); off += (size_t)4*512*512*2;    // 2 MB
  u8*  qb   = (u8*)(ws + off);  off += (size_t)16*1024*1024;   // Q fp8 (8MB used)
  u8*  ktb  = (u8*)(ws + off);  off += (size_t)16*1024*1024;   // K fp8 tiled (8MB used)
  u16* vtb  = (u16*)(ws + off); off += (size_t)16*1024*1024;   // V bf16 tiled

  gn_stats<<<128, 256, 0, stream>>>(x, stats);
  gn_apply_T<<<dim3(128, 16, 4), 256, 0, stream>>>(x, stats, gamma, beta, tbuf);
  w2bf<<<1024, 256, 0, stream>>>(wq_w, wk_w, wv_w, out_w, Wcat);
  u16* Wo = Wcat + 3*512*512;
  qkv_gemm<<<dim3(128, 12), 256, 0, stream>>>(tbuf, Wcat, wq_b, wk_b, wv_b,
                                              qb, ktb, vtb);
  attn_fwd<<<dim3(128, 4), 256, 0, stream>>>(qb, ktb, vtb, tbuf);
  out_gemm<<<dim3(128, 4), 256, 0, stream>>>(tbuf, Wo, out_b, (float*)d_out, x);
}

// Round 7
// 325.317 us; speedup vs baseline: 5.0556x; 1.1205x over previous
//
#include <hip/hip_runtime.h>
#include <hip/hip_fp8.h>

typedef unsigned short u16;
typedef unsigned char u8;
typedef unsigned int u32;
typedef short bf16x8 __attribute__((ext_vector_type(8)));
typedef float f32x4 __attribute__((ext_vector_type(4)));
typedef u16 u16x4 __attribute__((ext_vector_type(4)));

#define SCALE_Q 0.044194173824159216f   // 1/sqrt(512)

// barrier WITHOUT vmcnt drain (lgkm only): in-flight global/DMA ops survive.
#define BAR() asm volatile("s_waitcnt lgkmcnt(0)\n\ts_barrier" ::: "memory")

__device__ __forceinline__ u16 f2b(float f){   // fp32 -> bf16 RNE
  unsigned u = __float_as_uint(f);
  u += 0x7fffu + ((u >> 16) & 1u);
  return (u16)(u >> 16);
}

__device__ __forceinline__ u8 f2e4(float f){   // fp32 -> fp8 e4m3 (OCP)
  return __hip_fp8_e4m3(f).__x;
}

__device__ __forceinline__ void gload16(const void* g, void* l){
  __builtin_amdgcn_global_load_lds(
      (const __attribute__((address_space(1))) void*)g,
      (__attribute__((address_space(3))) void*)l, 16, 0, 0);
}

__device__ __forceinline__ float qsum16(float v){
  v += __shfl_xor(v, 1); v += __shfl_xor(v, 2);
  v += __shfl_xor(v, 4); v += __shfl_xor(v, 8);
  return v;
}

// ---------------- GroupNorm stats: one block per (b, group) ----------------
__global__ __launch_bounds__(256) void gn_stats(const float* __restrict__ x,
                                                float* __restrict__ stats){
  int bg = blockIdx.x;
  const float4* p4 = (const float4*)(x + (size_t)bg * 65536);
  float s = 0.f, ss = 0.f;
  for (int i = threadIdx.x; i < 16384; i += 256){
    float4 v = p4[i];
    s  += v.x + v.y + v.z + v.w;
    ss += v.x*v.x + v.y*v.y + v.z*v.z + v.w*v.w;
  }
  for (int off = 32; off; off >>= 1){
    s  += __shfl_down(s, off);
    ss += __shfl_down(ss, off);
  }
  __shared__ float as_[4], bs_[4];
  int wid = threadIdx.x >> 6, lid = threadIdx.x & 63;
  if (lid == 0){ as_[wid] = s; bs_[wid] = ss; }
  __syncthreads();
  if (threadIdx.x == 0){
    float S = as_[0]+as_[1]+as_[2]+as_[3], SS = bs_[0]+bs_[1]+bs_[2]+bs_[3];
    float mean = S * (1.f/65536.f);
    float var  = SS * (1.f/65536.f) - mean*mean;
    stats[2*bg]   = mean;
    stats[2*bg+1] = rsqrtf(var + 1e-6f);
  }
}

// ------- normalize + affine + transpose [b,c,N] -> t[b,N,c] (bf16) ---------
__global__ __launch_bounds__(256) void gn_apply_T(const float* __restrict__ x,
                                                  const float* __restrict__ stats,
                                                  const float* __restrict__ gamma,
                                                  const float* __restrict__ beta,
                                                  u16* __restrict__ t){
  __shared__ float tile[32][33];
  int nb = blockIdx.x, cb = blockIdx.y, b = blockIdx.z;
  int tx = threadIdx.x & 31, ty = threadIdx.x >> 5;
  int n0 = nb * 32, c0 = cb * 32;
  #pragma unroll
  for (int i = 0; i < 4; i++){
    int ch = c0 + ty + i*8;
    float mean = stats[2*((b<<5) + (ch>>4))];
    float rstd = stats[2*((b<<5) + (ch>>4)) + 1];
    float v = x[(((size_t)b*512 + ch) << 12) + n0 + tx];
    tile[ty + i*8][tx] = (v - mean) * rstd * gamma[ch] + beta[ch];
  }
  __syncthreads();
  #pragma unroll
  for (int i = 0; i < 4; i++){
    int n = n0 + ty + i*8;
    int ch = c0 + tx;
    t[((size_t)((b<<12) + n))*512 + ch] = f2b(tile[tx][ty + i*8]);
  }
}

// ---------------- fp32 -> bf16 weight conversion (4 matrices) --------------
__global__ __launch_bounds__(256) void w2bf(const float* __restrict__ a,
                                            const float* __restrict__ b,
                                            const float* __restrict__ c,
                                            const float* __restrict__ d,
                                            u16* __restrict__ o){
  int idx = blockIdx.x * 256 + threadIdx.x;
  int which = idx >> 16;
  const float4* src = (const float4*)(which == 0 ? a : which == 1 ? b : which == 2 ? c : d);
  float4 v = src[idx & 65535];
  u16x4 pk;
  pk.x = f2b(v.x); pk.y = f2b(v.y); pk.z = f2b(v.z); pk.w = f2b(v.w);
  *(u16x4*)(o + (size_t)idx*4) = pk;
}

// ------------- fused QKV gemm: grid (128, 12); y>>2 selects matrix ---------
// mat 0 -> Q fp8 e4m3 [b,tok,c] (unscaled)
// mat 1 -> K fp8 tiled [b][tile64][ks16][kr64][ch32], chunk swz = q4^((kr>>2)&3)
// mat 2 -> V fp8 tiled [b][tile64][c512][kv64], chunk swz = chunk^(n&7)
// K/V epilogues staged through LDS -> coalesced dwordx4 global stores.
__global__ __launch_bounds__(256, 2) void qkv_gemm(const u16* __restrict__ A,
                                                   const u16* __restrict__ Wcat,
                                                   const float* __restrict__ qbias,
                                                   const float* __restrict__ kbias,
                                                   const float* __restrict__ vbias,
                                                   u8* __restrict__ qo,
                                                   u8* __restrict__ ko,
                                                   u8* __restrict__ vo){
  __shared__ __align__(16) u16 SMEM[8192];     // As | Bs, reused as 16KB stage
  u16* As = SMEM;
  u16* Bs = SMEM + 4096;
  const int t = threadIdx.x;
  const int w = t >> 6, ln = t & 63;
  const int wr = w >> 1, wc = w & 1;
  const int q4 = ln >> 4, l15 = ln & 15;
  const int y = blockIdx.y;
  const int mat = y >> 2, yb = y & 3;
  const int row0 = blockIdx.x * 128;
  const u16* Ab = A    + (size_t)row0 * 512;
  const u16* Bb = Wcat + (size_t)y * 128 * 512;
  f32x4 acc[4][4];
  #pragma unroll
  for (int i = 0; i < 4; i++)
    #pragma unroll
    for (int j = 0; j < 4; j++){
      acc[i][j][0]=0.f; acc[i][j][1]=0.f; acc[i][j][2]=0.f; acc[i][j][3]=0.f;
    }
  for (int kt = 0; kt < 16; ++kt){
    #pragma unroll
    for (int i = 0; i < 2; i++){
      int idx = i*256 + t;
      gload16(Ab + (size_t)(idx>>2)*512 + kt*32 + (idx&3)*8, As + (size_t)idx*8);
      gload16(Bb + (size_t)(idx>>2)*512 + kt*32 + (idx&3)*8, Bs + (size_t)idx*8);
    }
    __syncthreads();
    bf16x8 af[4], bf[4];
    #pragma unroll
    for (int mt = 0; mt < 4; mt++)
      af[mt] = *(const bf16x8*)(As + (wr*64 + mt*16 + l15)*32 + q4*8);
    #pragma unroll
    for (int nt = 0; nt < 4; nt++)
      bf[nt] = *(const bf16x8*)(Bs + (wc*64 + nt*16 + l15)*32 + q4*8);
    #pragma unroll
    for (int mt = 0; mt < 4; mt++)
      #pragma unroll
      for (int nt = 0; nt < 4; nt++)
        acc[mt][nt] = __builtin_amdgcn_mfma_f32_16x16x32_bf16(af[mt], bf[nt], acc[mt][nt], 0, 0, 0);
    __syncthreads();
  }
  const int bb = row0 >> 12;            // batch
  const int tile0 = (row0 >> 6) & 63;   // first 64-token tile of this block
  const int col0 = yb*128 + wc*64;      // global channel base for this wave
  u8* Ls = (u8*)SMEM;                   // 16KB staging

  if (mat == 0){
    #pragma unroll
    for (int nt = 0; nt < 4; nt++){
      int n = col0 + nt*16 + l15;
      float bv = qbias[n];
      #pragma unroll
      for (int mt = 0; mt < 4; mt++){
        int m0 = row0 + wr*64 + mt*16 + q4*4;
        #pragma unroll
        for (int r = 0; r < 4; r++)
          qo[(size_t)(m0 + r)*512 + n] = f2e4(acc[mt][nt][r] + bv);
      }
    }
  } else if (mat == 1){
    // stage into LDS in exact global within-tile layout
    #pragma unroll
    for (int nt = 0; nt < 4; nt++){
      int n = col0 + nt*16 + l15;
      float bv = kbias[n];
      int ksl = wc*2 + (nt >> 1);            // block-local ks (0..3)
      int c3  = ((nt & 1)*2 + (l15 >> 3));   // ch>>3 within 32-ch group
      #pragma unroll
      for (int mt = 0; mt < 4; mt++){
        #pragma unroll
        for (int r = 0; r < 4; r++){
          int kr = mt*16 + q4*4 + r;
          int chunk = c3 ^ ((kr >> 2) & 3);
          Ls[(wr*4 + ksl)*2048 + kr*32 + chunk*8 + (l15 & 7)] = f2e4(acc[mt][nt][r] + bv);
        }
      }
    }
    __syncthreads();
    #pragma unroll
    for (int i = 0; i < 4; i++){
      int ci = i*256 + t;                    // 16B chunk 0..1023
      int ri = ci >> 7, t2 = ri >> 2, ksl2 = ri & 3;
      u8* dst = ko + ((size_t)(bb*64 + tile0 + t2))*32768
                   + (size_t)(yb*4 + ksl2)*2048 + (size_t)(ci & 127)*16;
      *(float4*)dst = *(const float4*)(Ls + (size_t)ci*16);
    }
  } else {
    #pragma unroll
    for (int nt = 0; nt < 4; nt++){
      int n = col0 + nt*16 + l15;
      float bv = vbias[n];
      int nl = n & 127;
      #pragma unroll
      for (int mt = 0; mt < 4; mt++){
        int kv = mt*16 + q4*4;
        u32 pk = (u32)f2e4(acc[mt][nt][0] + bv)
               | ((u32)f2e4(acc[mt][nt][1] + bv) << 8)
               | ((u32)f2e4(acc[mt][nt][2] + bv) << 16)
               | ((u32)f2e4(acc[mt][nt][3] + bv) << 24);
        int phys = (kv >> 3) ^ (n & 7);
        *(u32*)(Ls + wr*8192 + nl*64 + phys*8 + (kv & 4)) = pk;
      }
    }
    __syncthreads();
    #pragma unroll
    for (int i = 0; i < 4; i++){
      int ci = i*256 + t;                    // 16B chunk 0..1023
      int t2 = ci >> 9;
      u8* dst = vo + ((size_t)(bb*64 + tile0 + t2))*32768
                   + (size_t)yb*8192 + (size_t)(ci & 511)*16;
      *(float4*)dst = *(const float4*)(Ls + (size_t)ci*16);
    }
  }
}

// ----------- out-proj gemm + bias + residual + transpose (fp32 out) --------
__global__ __launch_bounds__(256, 2) void out_gemm(const u16* __restrict__ A,
                                                   const u16* __restrict__ Bw,
                                                   const float* __restrict__ bias,
                                                   float* __restrict__ out,
                                                   const float* __restrict__ resid){
  __shared__ __align__(16) u16 As[128*32];
  __shared__ __align__(16) u16 Bs[128*32];
  const int t = threadIdx.x;
  const int w = t >> 6, ln = t & 63;
  const int wr = w >> 1, wc = w & 1;
  const int q4 = ln >> 4, l15 = ln & 15;
  const u16* Ab = A  + (size_t)blockIdx.x * 128 * 512;
  const u16* Bb = Bw + (size_t)blockIdx.y * 128 * 512;
  f32x4 acc[4][4];
  #pragma unroll
  for (int i = 0; i < 4; i++)
    #pragma unroll
    for (int j = 0; j < 4; j++){
      acc[i][j][0]=0.f; acc[i][j][1]=0.f; acc[i][j][2]=0.f; acc[i][j][3]=0.f;
    }
  for (int kt = 0; kt < 16; ++kt){
    #pragma unroll
    for (int i = 0; i < 2; i++){
      int idx = i*256 + t;
      gload16(Ab + (size_t)(idx>>2)*512 + kt*32 + (idx&3)*8, As + (size_t)idx*8);
      gload16(Bb + (size_t)(idx>>2)*512 + kt*32 + (idx&3)*8, Bs + (size_t)idx*8);
    }
    __syncthreads();
    bf16x8 af[4], bf[4];
    #pragma unroll
    for (int mt = 0; mt < 4; mt++)
      af[mt] = *(const bf16x8*)(As + (wr*64 + mt*16 + l15)*32 + q4*8);
    #pragma unroll
    for (int nt = 0; nt < 4; nt++)
      bf[nt] = *(const bf16x8*)(Bs + (wc*64 + nt*16 + l15)*32 + q4*8);
    #pragma unroll
    for (int mt = 0; mt < 4; mt++)
      #pragma unroll
      for (int nt = 0; nt < 4; nt++)
        acc[mt][nt] = __builtin_amdgcn_mfma_f32_16x16x32_bf16(af[mt], bf[nt], acc[mt][nt], 0, 0, 0);
    __syncthreads();
  }
  const int row0 = blockIdx.x*128 + wr*64;
  const int col0 = blockIdx.y*128 + wc*64;
  #pragma unroll
  for (int nt = 0; nt < 4; nt++){
    int n = col0 + nt*16 + l15;
    float bv = bias[n];
    #pragma unroll
    for (int mt = 0; mt < 4; mt++){
      int m0 = row0 + mt*16 + q4*4;
      int bb = m0 >> 12, tok = m0 & 4095;
      size_t base = (((size_t)(bb*512 + n)) << 12) + tok;
      float4 xr = *(const float4*)(resid + base);
      float4 ov;
      ov.x = acc[mt][nt][0] + bv + xr.x;
      ov.y = acc[mt][nt][1] + bv + xr.y;
      ov.z = acc[mt][nt][2] + bv + xr.z;
      ov.w = acc[mt][nt][3] + bv + xr.w;
      *(float4*)(out + base) = ov;
    }
  }
}

// ---------------------------- flash attention ------------------------------
// q fp8 [b,tok,512]; kt fp8 tiled [b][64][ks16][kr64][ch32] (swizzled);
// vt fp8 tiled [b][64][c512][kv64] (swizzled); out O bf16 [b,tok,512].
// BM=32, BN=64, 256 threads (4 waves), 2 blocks/CU, 64 iterations.
// All-fp8 MFMA (S and PV). Split-S: 4 independent 8-deep accumulator chains.
// K dbuf via global_load_lds (full-iter cover); V early-issued from L2 into
// regs; P round-trips LDS as fp8. Max-free softmax.
__global__ __launch_bounds__(256, 2) void attn_fwd(const u8* __restrict__ q,
                                                   const u8* __restrict__ kt,
                                                   const u8* __restrict__ vt,
                                                   u16* __restrict__ outO){
  __shared__ __align__(16) u8 Kb[2][32768];    // 2 x 32KB fp8 K tiles
  __shared__ __align__(16) u8 Pb[32*72];       // P fp8 [qrow32][kv64 +8 pad]
  __shared__ __align__(16) float lL[64];       // [chh][row32]

  const int t = threadIdx.x, w = t >> 6, ln = t & 63;
  const int q4 = ln >> 4, l15 = ln & 15;
  const int rt = w >> 1, chh = w & 1;          // S role: row-tile, col-half
  const int b = blockIdx.y, q0 = blockIdx.x * 32;
  const u8* kbase = kt + ((size_t)b << 21);
  const u8* vbase = vt + ((size_t)b << 21);

  // Q fragments fp8: rows q0 + rt*16 + l15, all 512 ch (32 VGPR)
  long qf[16];
  {
    const u8* qr = q + (size_t)((b<<12) + q0 + rt*16 + l15) * 512;
    #pragma unroll
    for (int ks = 0; ks < 16; ks++) qf[ks] = *(const long*)(qr + ks*32 + q4*8);
  }
  f32x4 oacc[2][8];
  #pragma unroll
  for (int i = 0; i < 2; i++)
    #pragma unroll
    for (int j = 0; j < 8; j++){
      oacc[i][j][0]=0.f; oacc[i][j][1]=0.f; oacc[i][j][2]=0.f; oacc[i][j][3]=0.f;
    }
  f32x4 lrow; lrow[0]=0.f; lrow[1]=0.f; lrow[2]=0.f; lrow[3]=0.f;

  // K-tile read offsets (two col-tiles per wave), swizzle baked in layout
  const int kr0 = chh*32 + l15,  kr1 = chh*32 + 16 + l15;
  const int ko0 = kr0*32 + ((q4 ^ ((kr0 >> 2) & 3)) << 3);
  const int ko1 = kr1*32 + ((q4 ^ ((kr1 >> 2) & 3)) << 3);

  // prologue: DMA K tile 0 into Kb[0] (2048 x 16B chunks, 8 per thread)
  #pragma unroll
  for (int i = 0; i < 8; i++){
    int ci = i*256 + t;
    gload16(kbase + (size_t)ci*16, &Kb[0][ci*16]);
  }
  __syncthreads();

  #pragma unroll 1
  for (int j = 0; j < 64; ++j){
    // 1. issue DMA for K tile j+1 (other buffer; full-iter latency cover)
    {
      const u8* kn = kbase + ((size_t)((j + 1) & 63) << 15);
      u8* kd = Kb[(j + 1) & 1];
      #pragma unroll
      for (int i = 0; i < 8; i++){
        int ci = i*256 + t;
        gload16(kn + (size_t)ci*16, kd + ci*16);
      }
    }
    // 2. V fragment loads from L2 EARLY (fp8, swizzled chunks)
    long vf0[8], vf1[8];
    {
      const u8* vtile = vbase + ((size_t)j << 15);
      #pragma unroll
      for (int ct = 0; ct < 8; ct++){
        int ch = 128*w + ct*16 + l15;
        int swz = ch & 7;
        const u8* vr = vtile + (size_t)ch*64;
        vf0[ct] = *(const long*)(vr + ((q4 ^ swz) << 3));
        vf1[ct] = *(const long*)(vr + (((4 + q4) ^ swz) << 3));
      }
    }
    // 3. S = Q K^T (fp8): 4 independent chains (2 col-tiles x even/odd ks)
    const u8* Kp = Kb[j & 1];
    f32x4 sA0, sA1, sB0, sB1;
    sA0[0]=0.f;sA0[1]=0.f;sA0[2]=0.f;sA0[3]=0.f;
    sA1[0]=0.f;sA1[1]=0.f;sA1[2]=0.f;sA1[3]=0.f;
    sB0[0]=0.f;sB0[1]=0.f;sB0[2]=0.f;sB0[3]=0.f;
    sB1[0]=0.f;sB1[1]=0.f;sB1[2]=0.f;sB1[3]=0.f;
    #pragma unroll
    for (int k2 = 0; k2 < 8; k2++){
      const u8* e0 = Kp + (2*k2)*2048;
      const u8* e1 = Kp + (2*k2 + 1)*2048;
      long ka0 = *(const long*)(e0 + ko0);
      long kb0 = *(const long*)(e0 + ko1);
      long ka1 = *(const long*)(e1 + ko0);
      long kb1 = *(const long*)(e1 + ko1);
      sA0 = __builtin_amdgcn_mfma_f32_16x16x32_fp8_fp8(qf[2*k2],   ka0, sA0, 0, 0, 0);
      sB0 = __builtin_amdgcn_mfma_f32_16x16x32_fp8_fp8(qf[2*k2],   kb0, sB0, 0, 0, 0);
      sA1 = __builtin_amdgcn_mfma_f32_16x16x32_fp8_fp8(qf[2*k2+1], ka1, sA1, 0, 0, 0);
      sB1 = __builtin_amdgcn_mfma_f32_16x16x32_fp8_fp8(qf[2*k2+1], kb1, sB1, 0, 0, 0);
    }
    // 4. max-free softmax -> P fp8 in LDS
    #pragma unroll
    for (int r = 0; r < 4; r++){
      float e0 = __expf((sA0[r] + sA1[r]) * SCALE_Q);
      float e1 = __expf((sB0[r] + sB1[r]) * SCALE_Q);
      lrow[r] += e0 + e1;
      int row = rt*16 + q4*4 + r;
      Pb[row*72 + chh*32 + l15]      = f2e4(e0);
      Pb[row*72 + chh*32 + 16 + l15] = f2e4(e1);
    }
    BAR();                                   // P visible; DMA + vf in flight
    // 5. PV (fp8): O += P V ; wave owns col strip [128w, 128w+128)
    {
      long pf00 = *(const long*)(Pb + l15*72 + q4*8);
      long pf01 = *(const long*)(Pb + l15*72 + 32 + q4*8);
      long pf10 = *(const long*)(Pb + (16 + l15)*72 + q4*8);
      long pf11 = *(const long*)(Pb + (16 + l15)*72 + 32 + q4*8);
      #pragma unroll
      for (int ct = 0; ct < 8; ct++){
        f32x4 a0 = oacc[0][ct], a1 = oacc[1][ct];
        a0 = __builtin_amdgcn_mfma_f32_16x16x32_fp8_fp8(pf00, vf0[ct], a0, 0, 0, 0);
        a1 = __builtin_amdgcn_mfma_f32_16x16x32_fp8_fp8(pf10, vf0[ct], a1, 0, 0, 0);
        a0 = __builtin_amdgcn_mfma_f32_16x16x32_fp8_fp8(pf01, vf1[ct], a0, 0, 0, 0);
        a1 = __builtin_amdgcn_mfma_f32_16x16x32_fp8_fp8(pf11, vf1[ct], a1, 0, 0, 0);
        oacc[0][ct] = a0; oacc[1][ct] = a1;
      }
    }
    __syncthreads();                         // drains DMA(j+1) (a full iter old)
  }

  // ---- epilogue: reduce l across lanes + the two col-half waves ----
  {
    f32x4 ls;
    #pragma unroll
    for (int r = 0; r < 4; r++) ls[r] = qsum16(lrow[r]);
    if (l15 == 0) *(f32x4*)&lL[chh*32 + rt*16 + q4*4] = ls;
  }
  __syncthreads();
  #pragma unroll
  for (int rr = 0; rr < 2; rr++){
    #pragma unroll
    for (int r = 0; r < 4; r++){
      int row = rr*16 + q4*4 + r;
      float inv = 1.f / (lL[row] + lL[32 + row]);
      u16* op = outO + ((size_t)b << 21) + (size_t)(q0 + row)*512 + 128*w + l15;
      #pragma unroll
      for (int ct = 0; ct < 8; ct++)
        op[ct*16] = f2b(oacc[rr][ct][r] * inv);
    }
  }
}

extern "C" void kernel_launch(void* const* d_in, const int* in_sizes, int n_in,
                              void* d_out, int out_size, void* d_ws, size_t ws_size,
                              hipStream_t stream){
  const float* x     = (const float*)d_in[0];
  const float* gamma = (const float*)d_in[1];
  const float* beta  = (const float*)d_in[2];
  const float* wq_w  = (const float*)d_in[3];
  const float* wq_b  = (const float*)d_in[4];
  const float* wk_w  = (const float*)d_in[5];
  const float* wk_b  = (const float*)d_in[6];
  const float* wv_w  = (const float*)d_in[7];
  const float* wv_b  = (const float*)d_in[8];
  const float* out_w = (const float*)d_in[9];
  const float* out_b = (const float*)d_in[10];

  char* ws = (char*)d_ws;
  float* stats = (float*)ws;                                   // 1 KB
  u16* tbuf = (u16*)(ws + 4096);                               // 16 MB (t, then O)
  size_t off = 4096 + (size_t)16*1024*1024;
  u16* Wcat = (u16*)(ws + off); off += (size_t)4*512*512*2;    // 2 MB
  u8*  qb   = (u8*)(ws + off);  off += (size_t)16*1024*1024;   // Q fp8
  u8*  ktb  = (u8*)(ws + off);  off += (size_t)16*1024*1024;   // K fp8 tiled
  u8*  vtb  = (u8*)(ws + off);  off += (size_t)16*1024*1024;   // V fp8 tiled

  gn_stats<<<128, 256, 0, stream>>>(x, stats);
  gn_apply_T<<<dim3(128, 16, 4), 256, 0, stream>>>(x, stats, gamma, beta, tbuf);
  w2bf<<<1024, 256, 0, stream>>>(wq_w, wk_w, wv_w, out_w, Wcat);
  u16* Wo = Wcat + 3*512*512;
  qkv_gemm<<<dim3(128, 12), 256, 0, stream>>>(tbuf, Wcat, wq_b, wk_b, wv_b,
                                              qb, ktb, vtb);
  attn_fwd<<<dim3(128, 4), 256, 0, stream>>>(qb, ktb, vtb, tbuf);
  out_gemm<<<dim3(128, 4), 256, 0, stream>>>(tbuf, Wo, out_b, (float*)d_out, x);
}